// Round 8
// baseline (493.838 us; speedup 1.0000x reference)
//
#include <hip/hip_runtime.h>
#include <hip/hip_bf16.h>

#define N_NODES 50000
#define N_EDGES 800000
#define FEAT 64
#define NRELS 8
#define NBUCK 196         // ceil(50000/256) buckets of 256 dst nodes (dst >> 8)
#define EPB 2048          // edges per bhist/bfill block

typedef __attribute__((ext_vector_type(8))) short bf16x8;   // 8 bf16 in 4 VGPRs
typedef __attribute__((ext_vector_type(4))) float f32x4;

static __host__ __device__ inline size_t align256(size_t x) { return (x + 255) & ~(size_t)255; }

__device__ inline unsigned short f2b(float f) {   // fp32 -> bf16 RNE
    unsigned u = __builtin_bit_cast(unsigned, f);
    unsigned r = (u + 0x7fffu + ((u >> 16) & 1u)) >> 16;
    return (unsigned short)r;
}
__device__ inline float b2f(unsigned short u) {   // bf16 -> fp32
    unsigned v = ((unsigned)u) << 16;
    return __builtin_bit_cast(float, v);
}

// ---------------------------------------------------------------------------
// Kernel 1: bucket-level histogram (196 bins) via LDS pre-aggregation.
// ---------------------------------------------------------------------------
__global__ void bhist_kernel(const int* __restrict__ dst, int* __restrict__ bcnt, int E) {
    __shared__ int bins[256];
    const int t = threadIdx.x;
    bins[t] = 0;
    __syncthreads();
    const int e0 = blockIdx.x * EPB;
#pragma unroll
    for (int k = 0; k < 8; k++) {
        int e = e0 + t + k * 256;
        if (e < E) atomicAdd(&bins[dst[e] >> 8], 1);
    }
    __syncthreads();
    if (t < NBUCK && bins[t]) atomicAdd(&bcnt[t], bins[t]);
}

// ---------------------------------------------------------------------------
// Kernel 2: one-block scan of 196 bucket counts -> boff[197] + cursor copy.
// ---------------------------------------------------------------------------
__global__ void bscan_kernel(const int* __restrict__ bcnt, int* __restrict__ boff,
                             int* __restrict__ bcur) {
    __shared__ int s[256];
    const int t = threadIdx.x;
    const int v = (t < NBUCK) ? bcnt[t] : 0;
    s[t] = v;
    __syncthreads();
    for (int o = 1; o < 256; o <<= 1) {
        int u = (t >= o) ? s[t - o] : 0;
        __syncthreads();
        s[t] += u;
        __syncthreads();
    }
    const int ex = s[t] - v;
    if (t < NBUCK) { boff[t] = ex; bcur[t] = ex; }
    if (t == NBUCK - 1) boff[NBUCK] = s[t];
}

// ---------------------------------------------------------------------------
// Kernel 3: bucket fill. Each block bins EPB edges by bucket into contiguous
// per-(block,bucket) runs reserved with one global atomic per bucket.
// Entry = src | et<<16 | (dst&255)<<19.  (runs avg ~10 entries -> dense lines)
// ---------------------------------------------------------------------------
__global__ void bfill_kernel(const int* __restrict__ dst, const int* __restrict__ srcv,
                             const int* __restrict__ et, int* __restrict__ bcur,
                             int* __restrict__ tmp, int E) {
    __shared__ int hist[256];
    __shared__ int base[256];
    __shared__ int lcur[256];
    const int t = threadIdx.x;
    hist[t] = 0; lcur[t] = 0;
    __syncthreads();
    const int e0 = blockIdx.x * EPB;
    int bk[8], pk[8];
#pragma unroll
    for (int k = 0; k < 8; k++) {
        int e = e0 + t + k * 256;
        if (e < E) {
            int dd = dst[e];
            bk[k] = dd >> 8;
            pk[k] = (srcv[e] & 0xFFFF) | (et[e] << 16) | ((dd & 255) << 19);
            atomicAdd(&hist[bk[k]], 1);
        } else bk[k] = -1;
    }
    __syncthreads();
    if (t < NBUCK && hist[t] > 0) base[t] = atomicAdd(&bcur[t], hist[t]);
    __syncthreads();
#pragma unroll
    for (int k = 0; k < 8; k++) {
        if (bk[k] >= 0) {
            int r = atomicAdd(&lcur[bk[k]], 1);
            tmp[base[bk[k]] + r] = pk[k];
        }
    }
}

// ---------------------------------------------------------------------------
// Kernel 4: hwb[r][n][f] (bf16) = feat[n,:] @ W[r], bf16 MFMA, all relations
// per block; feat tile + A-frags resident once; D staged via LDS -> b128 stores.
// ---------------------------------------------------------------------------
__global__ void hwb_kernel(const float* __restrict__ feat, const float* __restrict__ W,
                           unsigned short* __restrict__ hwb, int N) {
    __shared__ unsigned short Fl[64 * 72];   // [node][d]
    __shared__ unsigned short Wt[64 * 72];   // [f][d]  (W_r transposed)
    __shared__ unsigned short Dl[64 * 72];   // [node][f] store staging
    const int n0 = blockIdx.x * 64;
    const int t  = threadIdx.x;

    const float4* F4 = (const float4*)feat;
#pragma unroll
    for (int i = 0; i < 4; i++) {
        int idx = t + 256 * i;            // [0,1024)
        int n = idx >> 4;
        int c = idx & 15;
        int gn = n0 + n;
        float4 v = make_float4(0.f, 0.f, 0.f, 0.f);
        if (gn < N) v = F4[(size_t)gn * 16 + c];
        ushort4 b;
        b.x = f2b(v.x); b.y = f2b(v.y); b.z = f2b(v.z); b.w = f2b(v.w);
        *(ushort4*)&Fl[n * 72 + c * 4] = b;
    }
    __syncthreads();

    const int w    = t >> 6;          // wave 0..3 -> nodes w*16..w*16+15
    const int l    = t & 63;
    const int col  = l & 15;
    const int quad = l >> 4;

    const int arow = (w * 16 + col) * 72 + quad * 8;
    bf16x8 a0 = *(const bf16x8*)&Fl[arow];
    bf16x8 a1 = *(const bf16x8*)&Fl[arow + 32];

    for (int r = 0; r < NRELS; r++) {
        __syncthreads();
        const float4* W4 = (const float4*)(W + (size_t)r * 4096);
#pragma unroll
        for (int i = 0; i < 4; i++) {
            int idx = t + 256 * i;
            int d = idx >> 4;
            int f0 = (idx & 15) * 4;
            float4 v = W4[idx];
            Wt[(f0 + 0) * 72 + d] = f2b(v.x);
            Wt[(f0 + 1) * 72 + d] = f2b(v.y);
            Wt[(f0 + 2) * 72 + d] = f2b(v.z);
            Wt[(f0 + 3) * 72 + d] = f2b(v.w);
        }
        __syncthreads();

#pragma unroll
        for (int ft = 0; ft < 4; ft++) {
            const int brow = (ft * 16 + col) * 72 + quad * 8;
            bf16x8 b0 = *(const bf16x8*)&Wt[brow];
            bf16x8 b1 = *(const bf16x8*)&Wt[brow + 32];
            f32x4 acc = {0.f, 0.f, 0.f, 0.f};
            acc = __builtin_amdgcn_mfma_f32_16x16x32_bf16(a0, b0, acc, 0, 0, 0);
            acc = __builtin_amdgcn_mfma_f32_16x16x32_bf16(a1, b1, acc, 0, 0, 0);
#pragma unroll
            for (int i = 0; i < 4; i++)
                Dl[(w * 16 + quad * 4 + i) * 72 + ft * 16 + col] = f2b(acc[i]);
        }
        __syncthreads();

        unsigned short* dstp = hwb + ((size_t)r * N + n0) * 64;
#pragma unroll
        for (int j0 = 0; j0 < 2; j0++) {
            int j = t + 256 * j0;         // [0,512)
            int row = j >> 3, c = j & 7;
            if (n0 + row < N) {
                bf16x8 dv = *(const bf16x8*)&Dl[row * 72 + c * 8];
                *(bf16x8*)(dstp + row * 64 + c * 8) = dv;
            }
        }
    }
}

// ---------------------------------------------------------------------------
// Kernel 5: bucket reduce + epilogue. One block (1024 thr, 16 waves) per
// 256-node bucket. LDS acc[256][64] fp32 + deg counters. Each wave: 4
// independent edge gathers in flight (lane = dim, 128 B/row), LDS float
// atomics (lane->bank 2-way, free). Epilogue fuses relu(0.2f+0.8*sum/deg).
// Edge-level distribution -> no hub-node imbalance.
// ---------------------------------------------------------------------------
__global__ void __launch_bounds__(1024)
bucket_reduce_kernel(const int* __restrict__ boff, const int* __restrict__ tmp,
                     const unsigned short* __restrict__ hwb,
                     const float* __restrict__ feat, float* __restrict__ out, int N) {
    __shared__ float acc[256 * 64];   // 64 KB
    __shared__ int degs[256];
    const int b = blockIdx.x;
    const int t = threadIdx.x;

    for (int i = t; i < 256 * 64; i += 1024) acc[i] = 0.f;
    if (t < 256) degs[t] = 0;
    __syncthreads();

    const int s0 = boff[b], s1 = boff[b + 1];
    const int w = t >> 6, lane = t & 63;

    for (int base = s0 + w * 4; base < s1; base += 64) {
        const int m = min(4, s1 - base);
        int pk[4];
        float v[4];
#pragma unroll
        for (int k = 0; k < 4; k++)
            pk[k] = (k < m) ? tmp[base + k] : 0;
#pragma unroll
        for (int k = 0; k < 4; k++) {
            if (k < m) {
                int s = pk[k] & 0xFFFF, r = (pk[k] >> 16) & 7;
                v[k] = b2f(hwb[((size_t)r * N + s) * 64 + lane]);
            }
        }
#pragma unroll
        for (int k = 0; k < 4; k++) {
            if (k < m) {
                int dlo = (pk[k] >> 19) & 255;
                atomicAdd(&acc[dlo * 64 + lane], v[k]);
                if (lane == 0) atomicAdd(&degs[dlo], 1);
            }
        }
    }
    __syncthreads();

    // Epilogue: thread t -> node t>>2, dims (t&3)*16 .. +16 (4 float4s).
    const int nl = t >> 2;
    const int d0 = (t & 3) * 16;
    const int node = b * 256 + nl;
    if (node < N) {
        const int dg = degs[nl];
        const float inv = (dg > 0) ? (0.8f / (float)dg) : 0.f;
        const float4* fp = (const float4*)(feat + (size_t)node * 64 + d0);
        float4* op = (float4*)(out + (size_t)node * 64 + d0);
        const float* a = &acc[nl * 64 + d0];
#pragma unroll
        for (int j = 0; j < 4; j++) {
            float4 f = fp[j];
            float4 r;
            if (dg > 0) {
                r.x = fmaxf(0.2f * f.x + a[j * 4 + 0] * inv, 0.f);
                r.y = fmaxf(0.2f * f.y + a[j * 4 + 1] * inv, 0.f);
                r.z = fmaxf(0.2f * f.z + a[j * 4 + 2] * inv, 0.f);
                r.w = fmaxf(0.2f * f.w + a[j * 4 + 3] * inv, 0.f);
            } else {
                r = f;
            }
            op[j] = r;
        }
    }
}

// ---------------------------------------------------------------------------
// Fallback kernels (small workspace): on-the-fly transform + atomics (fp32).
// ---------------------------------------------------------------------------
__global__ void degf_kernel(const int* __restrict__ dst, float* __restrict__ deg, int E) {
    int e = blockIdx.x * blockDim.x + threadIdx.x;
    if (e < E) atomicAdd(deg + dst[e], 1.0f);
}

__global__ void otf_kernel(const int* __restrict__ src, const int* __restrict__ dst,
                           const int* __restrict__ et, const float* __restrict__ feat,
                           const float* __restrict__ W, float* __restrict__ out, int E) {
    int wid = (blockIdx.x * blockDim.x + threadIdx.x) >> 6;
    int l = threadIdx.x & 63;
    if (wid >= E) return;
    int s = src[wid], dd = dst[wid], r = et[wid];
    float fv = feat[(size_t)s * 64 + l];
    const float* Wr = W + (size_t)r * 4096;
    float acc = 0.f;
#pragma unroll
    for (int d = 0; d < 64; d++) {
        float a = __shfl(fv, d);
        acc += a * Wr[d * 64 + l];
    }
    atomicAdd(out + (size_t)dd * 64 + l, acc);
}

__global__ void final_kernel(const float* __restrict__ feat, const float* __restrict__ deg,
                             float* __restrict__ out, int N) {
    int i = blockIdx.x * blockDim.x + threadIdx.x;
    if (i >= N * 16) return;
    int n = i >> 4;
    float d = deg[n];
    float4 f = ((const float4*)feat)[i];
    float4 m = ((float4*)out)[i];
    float4 res;
    if (d > 0.f) {
        float inv = 0.8f / d;
        res.x = fmaxf(0.2f * f.x + m.x * inv, 0.f);
        res.y = fmaxf(0.2f * f.y + m.y * inv, 0.f);
        res.z = fmaxf(0.2f * f.z + m.z * inv, 0.f);
        res.w = fmaxf(0.2f * f.w + m.w * inv, 0.f);
    } else {
        res = f;
    }
    ((float4*)out)[i] = res;
}

extern "C" void kernel_launch(void* const* d_in, const int* in_sizes, int n_in,
                              void* d_out, int out_size, void* d_ws, size_t ws_size,
                              hipStream_t stream) {
    const float* feat = (const float*)d_in[0];   // [N, 64]
    const float* W    = (const float*)d_in[1];   // [8, 64, 64]
    const int*   src  = (const int*)d_in[2];     // [E]
    const int*   dst  = (const int*)d_in[3];     // [E]
    const int*   et   = (const int*)d_in[4];     // [E]
    float* out = (float*)d_out;                  // [N, 64]

    const int N = N_NODES, E = N_EDGES;

    // Workspace layout:
    char* p = (char*)d_ws;
    int* bcnt = (int*)p;  p += align256((size_t)NBUCK * 4);
    int* boff = (int*)p;  p += align256((size_t)(NBUCK + 1) * 4);
    int* bcur = (int*)p;  p += align256((size_t)NBUCK * 4);
    int* tmp  = (int*)p;  p += align256((size_t)E * 4);
    unsigned short* hwb = (unsigned short*)p;
    p += (size_t)NRELS * N * FEAT * 2;           // bf16 hw: 51.2 MB
    size_t need_full = (size_t)(p - (char*)d_ws);

    if (ws_size >= need_full) {
        hipMemsetAsync(bcnt, 0, (size_t)NBUCK * 4, stream);
        bhist_kernel<<<(E + EPB - 1) / EPB, 256, 0, stream>>>(dst, bcnt, E);
        bscan_kernel<<<1, 256, 0, stream>>>(bcnt, boff, bcur);
        bfill_kernel<<<(E + EPB - 1) / EPB, 256, 0, stream>>>(dst, src, et, bcur, tmp, E);
        hwb_kernel<<<(N + 63) / 64, 256, 0, stream>>>(feat, W, hwb, N);
        bucket_reduce_kernel<<<NBUCK, 1024, 0, stream>>>(boff, tmp, hwb, feat, out, N);
    } else {
        // Minimal-workspace fallback.
        float* deg = (float*)d_ws;
        hipMemsetAsync(out, 0, (size_t)N * FEAT * 4, stream);
        hipMemsetAsync(deg, 0, (size_t)N * 4, stream);
        degf_kernel<<<(E + 255) / 256, 256, 0, stream>>>(dst, deg, E);
        otf_kernel<<<(E + 3) / 4, 256, 0, stream>>>(src, dst, et, feat, W, out, E);
        final_kernel<<<(N * 16 + 255) / 256, 256, 0, stream>>>(feat, deg, out, N);
    }
}

// Round 9
// 173.823 us; speedup vs baseline: 2.8410x; 2.8410x over previous
//
#include <hip/hip_runtime.h>
#include <hip/hip_bf16.h>

#define N_NODES 50000
#define N_EDGES 800000
#define FEAT 64
#define NRELS 8
#define NBUCK 196         // ceil(50000/256) buckets of 256 dst nodes (dst >> 8)
#define EPB 2048          // edges per bhist/bfill block
#define NBP 391           // ceil(E / EPB) = number of bhist/bfill blocks

typedef __attribute__((ext_vector_type(8))) short bf16x8;   // 8 bf16 in 4 VGPRs
typedef __attribute__((ext_vector_type(4))) float f32x4;

static __host__ __device__ inline size_t align256(size_t x) { return (x + 255) & ~(size_t)255; }

__device__ inline unsigned short f2b(float f) {   // fp32 -> bf16 RNE
    unsigned u = __builtin_bit_cast(unsigned, f);
    unsigned r = (u + 0x7fffu + ((u >> 16) & 1u)) >> 16;
    return (unsigned short)r;
}
__device__ inline float b2f(unsigned short u) {   // bf16 -> fp32
    unsigned v = ((unsigned)u) << 16;
    return __builtin_bit_cast(float, v);
}

// ---------------------------------------------------------------------------
// Kernel 1: per-block partial bucket histograms (plain stores, no memset dep).
// bpart[block][NBUCK]
// ---------------------------------------------------------------------------
__global__ void bhist_kernel(const int* __restrict__ dst, int* __restrict__ bpart, int E) {
    __shared__ int bins[256];
    const int t = threadIdx.x;
    bins[t] = 0;
    __syncthreads();
    const int e0 = blockIdx.x * EPB;
#pragma unroll
    for (int k = 0; k < 8; k++) {
        int e = e0 + t + k * 256;
        if (e < E) atomicAdd(&bins[dst[e] >> 8], 1);
    }
    __syncthreads();
    if (t < NBUCK) bpart[blockIdx.x * NBUCK + t] = bins[t];
}

// ---------------------------------------------------------------------------
// Kernel 2: one block: sum NBP partials per bucket, scan 196 -> boff[197]+bcur.
// ---------------------------------------------------------------------------
__global__ void bscan_kernel(const int* __restrict__ bpart, int* __restrict__ boff,
                             int* __restrict__ bcur) {
    __shared__ int s[256];
    const int t = threadIdx.x;
    int total = 0;
    if (t < NBUCK)
        for (int b = 0; b < NBP; b++) total += bpart[b * NBUCK + t];
    s[t] = total;
    __syncthreads();
    for (int o = 1; o < 256; o <<= 1) {
        int u = (t >= o) ? s[t - o] : 0;
        __syncthreads();
        s[t] += u;
        __syncthreads();
    }
    const int ex = s[t] - total;
    if (t < NBUCK) { boff[t] = ex; bcur[t] = ex; }
    if (t == NBUCK - 1) boff[NBUCK] = s[t];
}

// ---------------------------------------------------------------------------
// Kernel 3: bucket fill. Each block bins EPB edges by bucket into contiguous
// per-(block,bucket) runs reserved with one global atomic per bucket.
// Entry = src | et<<16 | (dst&255)<<19.
// ---------------------------------------------------------------------------
__global__ void bfill_kernel(const int* __restrict__ dst, const int* __restrict__ srcv,
                             const int* __restrict__ et, int* __restrict__ bcur,
                             int* __restrict__ tmp, int E) {
    __shared__ int hist[256];
    __shared__ int base[256];
    __shared__ int lcur[256];
    const int t = threadIdx.x;
    hist[t] = 0; lcur[t] = 0;
    __syncthreads();
    const int e0 = blockIdx.x * EPB;
    int bk[8], pk[8];
#pragma unroll
    for (int k = 0; k < 8; k++) {
        int e = e0 + t + k * 256;
        if (e < E) {
            int dd = dst[e];
            bk[k] = dd >> 8;
            pk[k] = (srcv[e] & 0xFFFF) | (et[e] << 16) | ((dd & 255) << 19);
            atomicAdd(&hist[bk[k]], 1);
        } else bk[k] = -1;
    }
    __syncthreads();
    if (t < NBUCK && hist[t] > 0) base[t] = atomicAdd(&bcur[t], hist[t]);
    __syncthreads();
#pragma unroll
    for (int k = 0; k < 8; k++) {
        if (bk[k] >= 0) {
            int r = atomicAdd(&lcur[bk[k]], 1);
            tmp[base[bk[k]] + r] = pk[k];
        }
    }
}

// ---------------------------------------------------------------------------
// Kernel 4: per-bucket exact sort + per-node offset build. One block/bucket.
// Counts per-node edges in LDS, scans 256 counts, writes off[] to global
// (replaces the old N-wide hist+scan chain), then places edges into spk.
// ---------------------------------------------------------------------------
__global__ void sort3_kernel(const int* __restrict__ boff, const int* __restrict__ tmp,
                             int* __restrict__ spk, int* __restrict__ off, int N) {
    __shared__ int s[256];
    __shared__ int cur[256];
    const int b = blockIdx.x;
    const int t = threadIdx.x;
    const int n0 = b * 256;
    const int nn = min(256, N - n0);
    const int s0 = boff[b], s1 = boff[b + 1];

    s[t] = 0;
    __syncthreads();
    for (int i = s0 + t; i < s1; i += 256)
        atomicAdd(&s[(tmp[i] >> 19) & 255], 1);
    __syncthreads();
    const int myc = s[t];
    // Hillis-Steele inclusive scan over 256 counts
    for (int o = 1; o < 256; o <<= 1) {
        int u = (t >= o) ? s[t - o] : 0;
        __syncthreads();
        s[t] += u;
        __syncthreads();
    }
    const int ex = s0 + s[t] - myc;   // global exclusive offset for node n0+t
    if (t < nn) { off[n0 + t] = ex; cur[t] = ex; }
    if (t == 0) off[n0 + nn] = s1;    // boundary (dup same-value write is benign)
    __syncthreads();
    for (int i = s0 + t; i < s1; i += 256) {
        int e = tmp[i];
        int pos = atomicAdd(&cur[(e >> 19) & 255], 1);
        spk[pos] = e;
    }
}

// ---------------------------------------------------------------------------
// Kernel 5: hwb[r][n][f] (bf16) = feat[n,:] @ W[r], bf16 MFMA, all relations
// per block; feat tile + A-frags resident once; D staged via LDS -> b128 stores.
// (R5 known-good)
// ---------------------------------------------------------------------------
__global__ void hwb_kernel(const float* __restrict__ feat, const float* __restrict__ W,
                           unsigned short* __restrict__ hwb, int N) {
    __shared__ unsigned short Fl[64 * 72];   // [node][d]
    __shared__ unsigned short Wt[64 * 72];   // [f][d]  (W_r transposed)
    __shared__ unsigned short Dl[64 * 72];   // [node][f] store staging
    const int n0 = blockIdx.x * 64;
    const int t  = threadIdx.x;

    const float4* F4 = (const float4*)feat;
#pragma unroll
    for (int i = 0; i < 4; i++) {
        int idx = t + 256 * i;            // [0,1024)
        int n = idx >> 4;
        int c = idx & 15;
        int gn = n0 + n;
        float4 v = make_float4(0.f, 0.f, 0.f, 0.f);
        if (gn < N) v = F4[(size_t)gn * 16 + c];
        ushort4 b;
        b.x = f2b(v.x); b.y = f2b(v.y); b.z = f2b(v.z); b.w = f2b(v.w);
        *(ushort4*)&Fl[n * 72 + c * 4] = b;
    }
    __syncthreads();

    const int w    = t >> 6;          // wave 0..3 -> nodes w*16..w*16+15
    const int l    = t & 63;
    const int col  = l & 15;
    const int quad = l >> 4;

    const int arow = (w * 16 + col) * 72 + quad * 8;
    bf16x8 a0 = *(const bf16x8*)&Fl[arow];
    bf16x8 a1 = *(const bf16x8*)&Fl[arow + 32];

    for (int r = 0; r < NRELS; r++) {
        __syncthreads();
        const float4* W4 = (const float4*)(W + (size_t)r * 4096);
#pragma unroll
        for (int i = 0; i < 4; i++) {
            int idx = t + 256 * i;
            int d = idx >> 4;
            int f0 = (idx & 15) * 4;
            float4 v = W4[idx];
            Wt[(f0 + 0) * 72 + d] = f2b(v.x);
            Wt[(f0 + 1) * 72 + d] = f2b(v.y);
            Wt[(f0 + 2) * 72 + d] = f2b(v.z);
            Wt[(f0 + 3) * 72 + d] = f2b(v.w);
        }
        __syncthreads();

#pragma unroll
        for (int ft = 0; ft < 4; ft++) {
            const int brow = (ft * 16 + col) * 72 + quad * 8;
            bf16x8 b0 = *(const bf16x8*)&Wt[brow];
            bf16x8 b1 = *(const bf16x8*)&Wt[brow + 32];
            f32x4 acc = {0.f, 0.f, 0.f, 0.f};
            acc = __builtin_amdgcn_mfma_f32_16x16x32_bf16(a0, b0, acc, 0, 0, 0);
            acc = __builtin_amdgcn_mfma_f32_16x16x32_bf16(a1, b1, acc, 0, 0, 0);
#pragma unroll
            for (int i = 0; i < 4; i++)
                Dl[(w * 16 + quad * 4 + i) * 72 + ft * 16 + col] = f2b(acc[i]);
        }
        __syncthreads();

        unsigned short* dstp = hwb + ((size_t)r * N + n0) * 64;
#pragma unroll
        for (int j0 = 0; j0 < 2; j0++) {
            int j = t + 256 * j0;         // [0,512)
            int row = j >> 3, c = j & 7;
            if (n0 + row < N) {
                bf16x8 dv = *(const bf16x8*)&Dl[row * 72 + c * 8];
                *(bf16x8*)(dstp + row * 64 + c * 8) = dv;
            }
        }
    }
}

// ---------------------------------------------------------------------------
// Kernel 6: fused gather-reduce + epilogue (R5 known-good). One wave per dst
// node, 8 edges in flight (g = lane>>3), 8-lane b128 row slices (q = lane&7).
// ---------------------------------------------------------------------------
__global__ void reduce_kernel(const int* __restrict__ off, const int* __restrict__ spk,
                              const unsigned short* __restrict__ hwb,
                              const float* __restrict__ feat,
                              float* __restrict__ out, int N) {
    const int node = blockIdx.x * 4 + (threadIdx.x >> 6);
    if (node >= N) return;
    const int lane = threadIdx.x & 63;
    const int g = lane >> 3, q = lane & 7;

    const int b = off[node], e = off[node + 1];
    const int deg = e - b;

    float acc[8] = {0.f, 0.f, 0.f, 0.f, 0.f, 0.f, 0.f, 0.f};
    for (int i = b + g; i < e; i += 8) {
        int pk = spk[i];
        int s = pk & 0xFFFF, r = (pk >> 16) & 7;
        bf16x8 u = *(const bf16x8*)(hwb + ((size_t)r * N + s) * 64 + q * 8);
#pragma unroll
        for (int k = 0; k < 8; k++) acc[k] += b2f((unsigned short)u[k]);
    }
#pragma unroll
    for (int k = 0; k < 8; k++) {
        acc[k] += __shfl_xor(acc[k], 8);
        acc[k] += __shfl_xor(acc[k], 16);
        acc[k] += __shfl_xor(acc[k], 32);
    }

    if (g == 0) {
        const float4* fp = (const float4*)feat + (size_t)node * 16 + q * 2;
        float4 f0 = fp[0], f1 = fp[1];
        float4 r0, r1;
        if (deg > 0) {
            float inv = 0.8f / (float)deg;
            r0.x = fmaxf(0.2f * f0.x + acc[0] * inv, 0.f);
            r0.y = fmaxf(0.2f * f0.y + acc[1] * inv, 0.f);
            r0.z = fmaxf(0.2f * f0.z + acc[2] * inv, 0.f);
            r0.w = fmaxf(0.2f * f0.w + acc[3] * inv, 0.f);
            r1.x = fmaxf(0.2f * f1.x + acc[4] * inv, 0.f);
            r1.y = fmaxf(0.2f * f1.y + acc[5] * inv, 0.f);
            r1.z = fmaxf(0.2f * f1.z + acc[6] * inv, 0.f);
            r1.w = fmaxf(0.2f * f1.w + acc[7] * inv, 0.f);
        } else {
            r0 = f0; r1 = f1;
        }
        float4* op = (float4*)out + (size_t)node * 16 + q * 2;
        op[0] = r0;
        op[1] = r1;
    }
}

// ---------------------------------------------------------------------------
// Fallback kernels (small workspace): on-the-fly transform + atomics (fp32).
// ---------------------------------------------------------------------------
__global__ void degf_kernel(const int* __restrict__ dst, float* __restrict__ deg, int E) {
    int e = blockIdx.x * blockDim.x + threadIdx.x;
    if (e < E) atomicAdd(deg + dst[e], 1.0f);
}

__global__ void otf_kernel(const int* __restrict__ src, const int* __restrict__ dst,
                           const int* __restrict__ et, const float* __restrict__ feat,
                           const float* __restrict__ W, float* __restrict__ out, int E) {
    int wid = (blockIdx.x * blockDim.x + threadIdx.x) >> 6;
    int l = threadIdx.x & 63;
    if (wid >= E) return;
    int s = src[wid], dd = dst[wid], r = et[wid];
    float fv = feat[(size_t)s * 64 + l];
    const float* Wr = W + (size_t)r * 4096;
    float acc = 0.f;
#pragma unroll
    for (int d = 0; d < 64; d++) {
        float a = __shfl(fv, d);
        acc += a * Wr[d * 64 + l];
    }
    atomicAdd(out + (size_t)dd * 64 + l, acc);
}

__global__ void final_kernel(const float* __restrict__ feat, const float* __restrict__ deg,
                             float* __restrict__ out, int N) {
    int i = blockIdx.x * blockDim.x + threadIdx.x;
    if (i >= N * 16) return;
    int n = i >> 4;
    float d = deg[n];
    float4 f = ((const float4*)feat)[i];
    float4 m = ((float4*)out)[i];
    float4 res;
    if (d > 0.f) {
        float inv = 0.8f / d;
        res.x = fmaxf(0.2f * f.x + m.x * inv, 0.f);
        res.y = fmaxf(0.2f * f.y + m.y * inv, 0.f);
        res.z = fmaxf(0.2f * f.z + m.z * inv, 0.f);
        res.w = fmaxf(0.2f * f.w + m.w * inv, 0.f);
    } else {
        res = f;
    }
    ((float4*)out)[i] = res;
}

extern "C" void kernel_launch(void* const* d_in, const int* in_sizes, int n_in,
                              void* d_out, int out_size, void* d_ws, size_t ws_size,
                              hipStream_t stream) {
    const float* feat = (const float*)d_in[0];   // [N, 64]
    const float* W    = (const float*)d_in[1];   // [8, 64, 64]
    const int*   src  = (const int*)d_in[2];     // [E]
    const int*   dst  = (const int*)d_in[3];     // [E]
    const int*   et   = (const int*)d_in[4];     // [E]
    float* out = (float*)d_out;                  // [N, 64]

    const int N = N_NODES, E = N_EDGES;

    // Workspace layout:
    char* p = (char*)d_ws;
    int* bpart = (int*)p;  p += align256((size_t)NBP * NBUCK * 4);
    int* boff  = (int*)p;  p += align256((size_t)(NBUCK + 1) * 4);
    int* bcur  = (int*)p;  p += align256((size_t)NBUCK * 4);
    int* off   = (int*)p;  p += align256((size_t)(N + 1) * 4);
    int* tmp   = (int*)p;  p += align256((size_t)E * 4);
    int* spk   = (int*)p;  p += align256((size_t)E * 4);
    unsigned short* hwb = (unsigned short*)p;
    p += (size_t)NRELS * N * FEAT * 2;           // bf16 hw: 51.2 MB
    size_t need_full = (size_t)(p - (char*)d_ws);

    if (ws_size >= need_full) {
        bhist_kernel<<<NBP, 256, 0, stream>>>(dst, bpart, E);
        bscan_kernel<<<1, 256, 0, stream>>>(bpart, boff, bcur);
        bfill_kernel<<<NBP, 256, 0, stream>>>(dst, src, et, bcur, tmp, E);
        sort3_kernel<<<NBUCK, 256, 0, stream>>>(boff, tmp, spk, off, N);
        hwb_kernel<<<(N + 63) / 64, 256, 0, stream>>>(feat, W, hwb, N);
        reduce_kernel<<<(N + 3) / 4, 256, 0, stream>>>(off, spk, hwb, feat, out, N);
    } else {
        // Minimal-workspace fallback.
        float* deg = (float*)d_ws;
        hipMemsetAsync(out, 0, (size_t)N * FEAT * 4, stream);
        hipMemsetAsync(deg, 0, (size_t)N * 4, stream);
        degf_kernel<<<(E + 255) / 256, 256, 0, stream>>>(dst, deg, E);
        otf_kernel<<<(E + 3) / 4, 256, 0, stream>>>(src, dst, et, feat, W, out, E);
        final_kernel<<<(N * 16 + 255) / 256, 256, 0, stream>>>(feat, deg, out, N);
    }
}